// Round 17
// baseline (219.897 us; speedup 1.0000x reference)
//
#include <hip/hip_runtime.h>
#include <hip/hip_fp16.h>
#include <stdint.h>

// HashEmbedder (Instant-NGP hash grid), MI355X gfx950.
// R16 -> R17 (4th submit; three GPUAcquisitionTimeouts — never ran).
// R16: 217.1us; embed 75us at rate 0.35 req/cyc/CU (< R14's
// 0.43) and FETCH up to 113MB. Diagnosis: L6 quad (4.26MB=101.6% L2) and
// L7 pair (4.20MB=100.2%) are at/over L2 capacity -> conflict misses at
// ~full random-access occupancy -> HBM-latency-degraded groups. R17:
// (a) L6 quad -> z-PAIR table (2.16MB, 51% of L2, ~0 misses; 4 gathers/pt
// instead of 2: +2M req but all L2-hit); (b) group {3,4,5} sequentially
// (3.63MB co-resident; R16 proved VGPR stays ~36); L7 unchanged (can't
// shrink below ~4.15MB). Requests 16.25M->17.5M but rate should recover
// to >=0.40. Predicted: embed ~67-71us, total ~208-214us. Falsifier:
// embed >=75us -> 0.35 is an intrinsic latency floor -> roofline call.

#define TABLE_SIZE (1u << 19)
#define TMASK (TABLE_SIZE - 1u)
#define P2 2654435761u
#define P3 805459861u

#define FSCALE 8192.0f
#define FINV   1.220703125e-4f   // 1/8192, exact pow2

// out scratch (dead after final kernel overwrites):
//   [256KB, ~3.9MB):  fp16 quad tables, levels 3..5 (uint4, SCALED x8192)
//   [16MB, ~18.2MB):  fp16 pair table, level 6 (uint2, SCALED)
//   [20MB, ~24.2MB):  fp16 pair table, level 7 (uint2, SCALED)
#define QUAD_BYTES_OFF  262144
#define PAIR6_BYTES_OFF 16777216
#define PAIR7_BYTES_OFF 20971520

// quad offsets (uint4 units): L3:0 L4:33792 L5:99392 end 226892 (3.63MB)
#define OFF_Q3 0
#define OFF_Q4 33792
#define OFF_Q5 99392

// fp16 dense tables L0+L1+L2 (packed scaled __half2 as uint32), in ws row 0:
// L0: [0,4913) DIM17, L1: [4913,14174) DIM21, L2: [14174,31750) DIM26
#define DENSE_L1_OFF 4913
#define DENSE_L2_OFF 14174
#define DENSE_E 31750
#define DENSE_BYTES (DENSE_E * 4)   // 127,000 B LDS

__device__ __forceinline__ uint32_t pack_s(float a, float b) {   // scale+pack
    __half2 h = __floats2half2_rn(a * FSCALE, b * FSCALE);
    return *(uint32_t*)&h;
}
__device__ __forceinline__ uint32_t pack_r(float a, float b) {   // raw pack
    __half2 h = __floats2half2_rn(a, b);
    return *(uint32_t*)&h;
}
__device__ __forceinline__ float2 h2f(uint32_t u) {
    __half2 h = *(__half2*)&u;
    return __half22float2(h);
}
__device__ __forceinline__ uint32_t getc(const uint4 v, int k) {
    return k == 0 ? v.x : k == 1 ? v.y : k == 2 ? v.z : v.w;
}

// ---------------- kernel 0: build all derived tables (one launch) ---------
// role (blockIdx.y): 0..2 -> quad L3..L5; 3 -> pair L6; 4 -> pair L7;
// 5 -> dense fp16 L0..L2
__global__ __launch_bounds__(256) void build_tables_kernel(
    const float* __restrict__ tables, uint32_t* __restrict__ dense,
    uint4* __restrict__ quads, uint2* __restrict__ pair6,
    uint2* __restrict__ pair7)
{
    const int role = (int)blockIdx.y;
    const int e = (int)blockIdx.x * 256 + (int)threadIdx.x;

    if (role < 3) {
        const int l = 3 + role;
        const int DK = (role == 0) ? 32 : (role == 1) ? 40 : 50;
        const int offq = (role == 0) ? OFF_Q3 : (role == 1) ? OFF_Q4 : OFF_Q5;
        const int E = (DK + 1) * DK * DK;
        if (e >= E) return;
        const int d2 = DK * DK;
        const int i = e / d2;
        const int rem = e - i * d2;
        const int j = rem / DK;
        const int k = rem - j * DK;
        const float2* __restrict__ tab = (const float2*)tables + (size_t)l * (size_t)TABLE_SIZE;
        const uint32_t hx  = (uint32_t)i;
        const uint32_t hy0 = (uint32_t)j * P2, hy1 = hy0 + P2;
        const uint32_t hz0 = (uint32_t)k * P3, hz1 = hz0 + P3;
        const float2 v00 = tab[(hx ^ hy0 ^ hz0) & TMASK];
        const float2 v01 = tab[(hx ^ hy0 ^ hz1) & TMASK];
        const float2 v10 = tab[(hx ^ hy1 ^ hz0) & TMASK];
        const float2 v11 = tab[(hx ^ hy1 ^ hz1) & TMASK];
        uint4 u;
        u.x = pack_s(v00.x, v00.y);
        u.y = pack_s(v01.x, v01.y);
        u.z = pack_s(v10.x, v10.y);
        u.w = pack_s(v11.x, v11.y);
        quads[offq + e] = u;
    } else if (role == 3) {
        // L6 z-pair: (i,j in 0..64, k in 0..63): {h2(z=k), h2(z=k+1)}
        const int E = 65 * 65 * 64;     // 270,400 (2.16MB)
        if (e >= E) return;
        const int i = e / 4160;         // 65*64
        const int rem = e - i * 4160;
        const int j = rem / 64;
        const int k = rem - j * 64;
        const float2* __restrict__ tab = (const float2*)tables + (size_t)6 * (size_t)TABLE_SIZE;
        const uint32_t hb = (uint32_t)i ^ ((uint32_t)j * P2);
        const float2 a = tab[(hb ^ ((uint32_t)k * P3)) & TMASK];
        const float2 b = tab[(hb ^ ((uint32_t)(k + 1) * P3)) & TMASK];
        uint2 u;
        u.x = pack_s(a.x, a.y);
        u.y = pack_s(b.x, b.y);
        pair6[e] = u;
    } else if (role == 4) {
        // L7 z-pair: (i,j in 0..80, k in 0..79)
        const int E = 81 * 81 * 80;     // 524,880 (4.2MB)
        if (e >= E) return;
        const int i = e / 6480;         // 81*80
        const int rem = e - i * 6480;
        const int j = rem / 80;
        const int k = rem - j * 80;
        const float2* __restrict__ tab = (const float2*)tables + (size_t)7 * (size_t)TABLE_SIZE;
        const uint32_t hb = (uint32_t)i ^ ((uint32_t)j * P2);
        const float2 a = tab[(hb ^ ((uint32_t)k * P3)) & TMASK];
        const float2 b = tab[(hb ^ ((uint32_t)(k + 1) * P3)) & TMASK];
        uint2 u;
        u.x = pack_s(a.x, a.y);
        u.y = pack_s(b.x, b.y);
        pair7[e] = u;
    } else {
        if (e >= DENSE_E) return;
        int lv, DIM, off;
        if (e < DENSE_L1_OFF)      { lv = 0; DIM = 17; off = 0; }
        else if (e < DENSE_L2_OFF) { lv = 1; DIM = 21; off = DENSE_L1_OFF; }
        else                       { lv = 2; DIM = 26; off = DENSE_L2_OFF; }
        const int le = e - off;
        const int d2 = DIM * DIM;
        const int i = le / d2;
        const int rem = le - i * d2;
        const int j = rem / DIM;
        const int k = rem - j * DIM;
        const uint32_t h = ((uint32_t)i ^ ((uint32_t)j * P2) ^ ((uint32_t)k * P3)) & TMASK;
        const float2* __restrict__ tab = (const float2*)tables + (size_t)lv * (size_t)TABLE_SIZE;
        const float2 v = tab[h];
        dense[e] = pack_s(v.x, v.y);
    }
}

// ---------------- 4-point quad embed (issue-all-then-interp, transient) ---
template<int DK>
__device__ __forceinline__ uint4 embed_quad4(const uint4* __restrict__ tab,
        const float px[4], const float py[4], const float pz[4])
{
    const float R = (float)DK;
    const float g = 1.0f / R;
    const int d2 = DK * DK;
    uint4 qa[4], qb[4];
    float wx[4], wy[4], wz[4];
#pragma unroll
    for (int k = 0; k < 4; ++k) {
        const float cx = fminf(fmaxf(px[k], 0.0f), 1.0f);
        const float cy = fminf(fmaxf(py[k], 0.0f), 1.0f);
        const float cz = fminf(fmaxf(pz[k], 0.0f), 1.0f);
        const int bx = min((int)floorf(cx * R), DK - 1);
        const int by = min((int)floorf(cy * R), DK - 1);
        const int bz = min((int)floorf(cz * R), DK - 1);
        wx[k] = (px[k] - (float)bx * g) * R;
        wy[k] = (py[k] - (float)by * g) * R;
        wz[k] = (pz[k] - (float)bz * g) * R;
        const int ia = (bx * DK + by) * DK + bz;
        qa[k] = tab[ia];
        qb[k] = tab[ia + d2];
    }
    uint32_t r[4];
#pragma unroll
    for (int k = 0; k < 4; ++k) {
        const float omx = 1.0f - wx[k], omy = 1.0f - wy[k], omz = 1.0f - wz[k];
        const float2 a00 = h2f(qa[k].x), a01 = h2f(qa[k].y);
        const float2 a10 = h2f(qa[k].z), a11 = h2f(qa[k].w);
        const float2 b00 = h2f(qb[k].x), b01 = h2f(qb[k].y);
        const float2 b10 = h2f(qb[k].z), b11 = h2f(qb[k].w);
        const float m00a = a00.x*omx + b00.x*wx[k], m00b = a00.y*omx + b00.y*wx[k];
        const float m01a = a01.x*omx + b01.x*wx[k], m01b = a01.y*omx + b01.y*wx[k];
        const float m10a = a10.x*omx + b10.x*wx[k], m10b = a10.y*omx + b10.y*wx[k];
        const float m11a = a11.x*omx + b11.x*wx[k], m11b = a11.y*omx + b11.y*wx[k];
        const float c0a = m00a*omz + m01a*wz[k], c0b = m00b*omz + m01b*wz[k];
        const float c1a = m10a*omz + m11a*wz[k], c1b = m10b*omz + m11b*wz[k];
        r[k] = pack_r(c0a*omy + c1a*wy[k], c0b*omy + c1b*wy[k]);
    }
    return make_uint4(r[0], r[1], r[2], r[3]);
}

// ---------------- 4-point pair embed, parameterized geometry --------------
// DIMJ = R+1 (i,j range), DIMK = R (z-cell count). Entry = z-pair.
template<int DIMJ, int DIMK>
__device__ __forceinline__ uint4 embed_pair4(const uint2* __restrict__ pairs,
        const float px[4], const float py[4], const float pz[4])
{
    const float R = (float)DIMK, g = 1.0f / R;
    const int jk = DIMJ * DIMK;
    uint2 d00[4], d01[4], d10[4], d11[4];
    float wx[4], wy[4], wz[4];
#pragma unroll
    for (int k = 0; k < 4; ++k) {
        const float cx = fminf(fmaxf(px[k], 0.0f), 1.0f);
        const float cy = fminf(fmaxf(py[k], 0.0f), 1.0f);
        const float cz = fminf(fmaxf(pz[k], 0.0f), 1.0f);
        const int bx = min((int)floorf(cx * R), DIMK - 1);
        const int by = min((int)floorf(cy * R), DIMK - 1);
        const int bz = min((int)floorf(cz * R), DIMK - 1);
        wx[k] = (px[k] - (float)bx * g) * R;
        wy[k] = (py[k] - (float)by * g) * R;
        wz[k] = (pz[k] - (float)bz * g) * R;
        const int ix = (bx * DIMJ + by) * DIMK + bz;
        d00[k] = pairs[ix];
        d01[k] = pairs[ix + DIMK];
        d10[k] = pairs[ix + jk];
        d11[k] = pairs[ix + jk + DIMK];
    }
    uint32_t r[4];
#pragma unroll
    for (int k = 0; k < 4; ++k) {
        const float omx = 1.0f - wx[k], omy = 1.0f - wy[k], omz = 1.0f - wz[k];
        const float2 a00 = h2f(d00[k].x), z00 = h2f(d00[k].y);
        const float2 a01 = h2f(d01[k].x), z01 = h2f(d01[k].y);
        const float2 a10 = h2f(d10[k].x), z10 = h2f(d10[k].y);
        const float2 a11 = h2f(d11[k].x), z11 = h2f(d11[k].y);
        const float c00a = a00.x*omz + z00.x*wz[k], c00b = a00.y*omz + z00.y*wz[k];
        const float c01a = a01.x*omz + z01.x*wz[k], c01b = a01.y*omz + z01.y*wz[k];
        const float c10a = a10.x*omz + z10.x*wz[k], c10b = a10.y*omz + z10.y*wz[k];
        const float c11a = a11.x*omz + z11.x*wz[k], c11b = a11.y*omz + z11.y*wz[k];
        const float e0a = c00a*omy + c01a*wy[k], e0b = c00b*omy + c01b*wy[k];
        const float e1a = c10a*omy + c11a*wy[k], e1b = c10b*omy + c11b*wy[k];
        r[k] = pack_r(e0a*omx + e1a*wx[k], e0b*omx + e1b*wx[k]);
    }
    return make_uint4(r[0], r[1], r[2], r[3]);
}

// ---------------- kernel 1: per-group gather embed ------------------------
// group 0: levels 3,4,5 sequentially (tables 3.63MB co-resident; x once).
// group 1: level 6 (pair, 2.16MB). group 2: level 7 (pair, 4.2MB).
// Group-major block order -> active table set L2-resident chip-wide.
__global__ __launch_bounds__(256, 4) void embed_levels_kernel(
    const float* __restrict__ x, const uint4* __restrict__ quads,
    const uint2* __restrict__ pair6, const uint2* __restrict__ pair7,
    uint32_t* __restrict__ wsh, int n, int bpl)
{
    const int bid = (int)blockIdx.x;
    const int grp = bid / bpl;
    const int pb = bid - grp * bpl;
    const int p0 = pb * 1024 + 4 * (int)threadIdx.x;
    if (p0 >= n) return;

    float px[4], py[4], pz[4];
    if (p0 + 4 <= n) {
        const float4* __restrict__ xv = (const float4*)(x + (size_t)3 * p0);
        const float4 f0 = xv[0], f1 = xv[1], f2 = xv[2];
        px[0] = f0.x; py[0] = f0.y; pz[0] = f0.z;
        px[1] = f0.w; py[1] = f1.x; pz[1] = f1.y;
        px[2] = f1.z; py[2] = f1.w; pz[2] = f2.x;
        px[3] = f2.y; py[3] = f2.z; pz[3] = f2.w;
    } else {
#pragma unroll
        for (int k = 0; k < 4; ++k) {
            const int i = min(p0 + k, n - 1);
            px[k] = x[3*i]; py[k] = x[3*i+1]; pz[k] = x[3*i+2];
        }
    }

    const int nstore = min(4, n - p0);

#define STORE_ROW(l, r) { \
    uint32_t* __restrict__ wl = wsh + (size_t)(l) * (size_t)n; \
    if (nstore == 4) *(uint4*)(wl + p0) = (r); \
    else for (int k = 0; k < nstore; ++k) wl[p0 + k] = getc((r), k); }

    if (grp == 0) {
        const uint4 r3 = embed_quad4<32>(quads + OFF_Q3, px, py, pz);
        STORE_ROW(3, r3)
        const uint4 r4 = embed_quad4<40>(quads + OFF_Q4, px, py, pz);
        STORE_ROW(4, r4)
        const uint4 r5 = embed_quad4<50>(quads + OFF_Q5, px, py, pz);
        STORE_ROW(5, r5)
    } else if (grp == 1) {
        const uint4 r6 = embed_pair4<65, 64>(pair6, px, py, pz);
        STORE_ROW(6, r6)
    } else {
        const uint4 r7 = embed_pair4<81, 80>(pair7, px, py, pz);
        STORE_ROW(7, r7)
    }
}

// ---------------- kernel 2: fused final (L0+L1+L2 LDS + rows 3..7 -> AoS) -
// 127KB fp16 dense in LDS; per thread: 4 points, 3 x loads, 5 uint4 ws
// loads, 16 f4 stores.
__global__ __launch_bounds__(1024) void final_kernel(
    const float* __restrict__ x, const uint32_t* wsh,
    float* __restrict__ out, int n)
{
    extern __shared__ uint32_t lds[];         // 31750 packed fp16 pairs
    for (int e = (int)threadIdx.x; e < DENSE_E; e += 1024) lds[e] = wsh[e];
    __syncthreads();

    const int p0 = ((int)blockIdx.x * 1024 + (int)threadIdx.x) * 4;
    if (p0 >= n) return;

    float px[4], py[4], pz[4];
    if (p0 + 4 <= n) {
        const float4* __restrict__ xv = (const float4*)(x + (size_t)3 * p0);
        const float4 f0 = xv[0], f1 = xv[1], f2 = xv[2];
        px[0] = f0.x; py[0] = f0.y; pz[0] = f0.z;
        px[1] = f0.w; py[1] = f1.x; pz[1] = f1.y;
        px[2] = f1.z; py[2] = f1.w; pz[2] = f2.x;
        px[3] = f2.y; py[3] = f2.z; pz[3] = f2.w;
    } else {
#pragma unroll
        for (int k = 0; k < 4; ++k) {
            const int i = min(p0 + k, n - 1);
            px[k] = x[3*i]; py[k] = x[3*i+1]; pz[k] = x[3*i+2];
        }
    }

    // issue the 5 ws row loads early (independent of LDS compute)
    uint4 v[5];
    if (p0 + 4 <= n) {
#pragma unroll
        for (int l = 0; l < 5; ++l)
            v[l] = *(const uint4*)(wsh + (size_t)(l + 3) * n + p0);
    } else {
#pragma unroll
        for (int l = 0; l < 5; ++l) {
            uint4 t;
            t.x = wsh[(size_t)(l+3)*n + min(p0+0, n-1)];
            t.y = wsh[(size_t)(l+3)*n + min(p0+1, n-1)];
            t.z = wsh[(size_t)(l+3)*n + min(p0+2, n-1)];
            t.w = wsh[(size_t)(l+3)*n + min(p0+3, n-1)];
            v[l] = t;
        }
    }

    // L0 (17), L1 (21), L2 (26) from fp16 LDS (scaled; unscale at write)
    float la[3][4], lb[3][4];
#pragma unroll
    for (int k = 0; k < 4; ++k) {
#pragma unroll
        for (int lv = 0; lv < 3; ++lv) {
            const float R  = (lv == 0) ? 16.f : (lv == 1) ? 20.f : 25.f;
            const int DIM  = (lv == 0) ? 17 : (lv == 1) ? 21 : 26;
            const int off  = (lv == 0) ? 0 : (lv == 1) ? DENSE_L1_OFF : DENSE_L2_OFF;
            const float g = 1.0f / R;
            const int D2 = DIM * DIM;
            const int bmax = DIM - 2;
            const float cx = fminf(fmaxf(px[k], 0.0f), 1.0f);
            const float cy = fminf(fmaxf(py[k], 0.0f), 1.0f);
            const float cz = fminf(fmaxf(pz[k], 0.0f), 1.0f);
            const int bx = min((int)floorf(cx * R), bmax);
            const int by = min((int)floorf(cy * R), bmax);
            const int bz = min((int)floorf(cz * R), bmax);
            const float wx = (px[k] - (float)bx * g) * R;
            const float wy = (py[k] - (float)by * g) * R;
            const float wz = (pz[k] - (float)bz * g) * R;
            const int c = off + (bx * DIM + by) * DIM + bz;
            const float2 e000 = h2f(lds[c]);
            const float2 e001 = h2f(lds[c + 1]);
            const float2 e010 = h2f(lds[c + DIM]);
            const float2 e011 = h2f(lds[c + DIM + 1]);
            const float2 e100 = h2f(lds[c + D2]);
            const float2 e101 = h2f(lds[c + D2 + 1]);
            const float2 e110 = h2f(lds[c + D2 + DIM]);
            const float2 e111 = h2f(lds[c + D2 + DIM + 1]);
            const float omx = 1.0f - wx, omy = 1.0f - wy, omz = 1.0f - wz;
            const float c00a = e000.x*omx + e100.x*wx, c00b = e000.y*omx + e100.y*wx;
            const float c01a = e001.x*omx + e101.x*wx, c01b = e001.y*omx + e101.y*wx;
            const float c10a = e010.x*omx + e110.x*wx, c10b = e010.y*omx + e110.y*wx;
            const float c11a = e011.x*omx + e111.x*wx, c11b = e011.y*omx + e111.y*wx;
            const float c0a = c00a*omy + c10a*wy, c0b = c00b*omy + c10b*wy;
            const float c1a = c01a*omy + c11a*wy, c1b = c01b*omy + c11b*wy;
            la[lv][k] = c0a*omz + c1a*wz;
            lb[lv][k] = c0b*omz + c1b*wz;
        }
    }

    // write AoS output
#pragma unroll
    for (int k = 0; k < 4; ++k) {
        if (p0 + k >= n) break;
        const float2 f3v = h2f(getc(v[0], k)), f4v = h2f(getc(v[1], k));
        const float2 f5v = h2f(getc(v[2], k)), f6v = h2f(getc(v[3], k));
        const float2 f7v = h2f(getc(v[4], k));
        float4* __restrict__ op = (float4*)(out + (size_t)(p0 + k) * 16);
        op[0] = make_float4(la[0][k]*FINV, lb[0][k]*FINV, la[1][k]*FINV, lb[1][k]*FINV);
        op[1] = make_float4(la[2][k]*FINV, lb[2][k]*FINV, f3v.x*FINV, f3v.y*FINV);
        op[2] = make_float4(f4v.x*FINV, f4v.y*FINV, f5v.x*FINV, f5v.y*FINV);
        op[3] = make_float4(f6v.x*FINV, f6v.y*FINV, f7v.x*FINV, f7v.y*FINV);
    }
}

// ---------------- fallback: monolithic, f32 exact -------------------------
__global__ __launch_bounds__(256) void hash_embed_mono_kernel(
    const float* __restrict__ x, const float* __restrict__ tables,
    float* __restrict__ out, int n)
{
    const int i = blockIdx.x * 256 + threadIdx.x;
    if (i >= n) return;
    const float px = x[3*i+0], py = x[3*i+1], pz = x[3*i+2];
    const float cx = fminf(fmaxf(px, 0.0f), 1.0f);
    const float cy = fminf(fmaxf(py, 0.0f), 1.0f);
    const float cz = fminf(fmaxf(pz, 0.0f), 1.0f);
    const float resf[8] = {16.f,20.f,25.f,32.f,40.f,50.f,64.f,80.f};
    float o[16];
#pragma unroll
    for (int l = 0; l < 8; ++l) {
        const float R = resf[l], g = 1.0f / R;
        const int bx = (int)floorf(cx*R), by = (int)floorf(cy*R), bz = (int)floorf(cz*R);
        const float wx = (px - bx*g)*R, wy = (py - by*g)*R, wz = (pz - bz*g)*R;
        const uint32_t hx0 = (uint32_t)bx, hx1 = hx0+1u;
        const uint32_t hy0 = (uint32_t)by*P2, hy1 = hy0+P2;
        const uint32_t hz0 = (uint32_t)bz*P3, hz1 = hz0+P3;
        const float2* tab = (const float2*)(tables) + (size_t)l*(size_t)TABLE_SIZE;
        const float2 e000 = tab[(hx0^hy0^hz0)&TMASK], e001 = tab[(hx0^hy0^hz1)&TMASK];
        const float2 e010 = tab[(hx0^hy1^hz0)&TMASK], e011 = tab[(hx0^hy1^hz1)&TMASK];
        const float2 e100 = tab[(hx1^hy0^hz0)&TMASK], e101 = tab[(hx1^hy0^hz1)&TMASK];
        const float2 e110 = tab[(hx1^hy1^hz0)&TMASK], e111 = tab[(hx1^hy1^hz1)&TMASK];
        const float omx = 1.f-wx, omy = 1.f-wy, omz = 1.f-wz;
        const float c00a = e000.x*omx + e100.x*wx, c00b = e000.y*omx + e100.y*wx;
        const float c01a = e001.x*omx + e101.x*wx, c01b = e001.y*omx + e101.y*wx;
        const float c10a = e010.x*omx + e110.x*wx, c10b = e010.y*omx + e110.y*wx;
        const float c11a = e011.x*omx + e111.x*wx, c11b = e011.y*omx + e111.y*wx;
        const float c0a = c00a*omy + c10a*wy, c0b = c00b*omy + c10b*wy;
        const float c1a = c01a*omy + c11a*wy, c1b = c01b*omy + c11b*wy;
        o[2*l+0] = c0a*omz + c1a*wz;
        o[2*l+1] = c0b*omz + c1b*wz;
    }
    float4* op = (float4*)(out + (size_t)i * 16);
    op[0] = make_float4(o[0],o[1],o[2],o[3]);
    op[1] = make_float4(o[4],o[5],o[6],o[7]);
    op[2] = make_float4(o[8],o[9],o[10],o[11]);
    op[3] = make_float4(o[12],o[13],o[14],o[15]);
}

extern "C" void kernel_launch(void* const* d_in, const int* in_sizes, int n_in,
                              void* d_out, int out_size, void* d_ws, size_t ws_size,
                              hipStream_t stream) {
    const float* x = (const float*)d_in[0];
    const float* tables = (const float*)d_in[1];
    float* out = (float*)d_out;
    const int n = in_sizes[0] / 3;  // 1048576 points

    // 127KB dynamic LDS needs opt-in; wsh needs 8*n*4B = 32MB.
    static int cap = -1;
    if (cap < 0) {
        cap = (hipFuncSetAttribute((const void*)final_kernel,
                  hipFuncAttributeMaxDynamicSharedMemorySize, DENSE_BYTES) == hipSuccess)
              ? 1 : 0;
    }
    const size_t ws_needed = (size_t)8 * (size_t)n * sizeof(uint32_t);  // 32 MB
    if (ws_size < ws_needed || cap == 0) {
        hash_embed_mono_kernel<<<(n + 255) / 256, 256, 0, stream>>>(x, tables, out, n);
        return;
    }

    uint32_t* wsh = (uint32_t*)d_ws;            // rows 3..7 used by embed
    uint32_t* dense = (uint32_t*)d_ws;          // dense fp16 in row-0 head (127KB)
    uint4*  quads = (uint4*)((char*)out + QUAD_BYTES_OFF);
    uint2*  pair6 = (uint2*)((char*)out + PAIR6_BYTES_OFF);
    uint2*  pair7 = (uint2*)((char*)out + PAIR7_BYTES_OFF);

    // k0: all derived tables, one launch
    build_tables_kernel<<<dim3(2051, 6), 256, 0, stream>>>(tables, dense, quads, pair6, pair7);

    // k1: per-group gather: {3,4,5} sequential, {6 pair}, {7 pair}
    const int bpl = (n + 1023) / 1024;
    embed_levels_kernel<<<3 * bpl, 256, 0, stream>>>(x, quads, pair6, pair7, wsh, n, bpl);

    // k2: fused final (L0+L1+L2 fp16 LDS + unpack rows 3..7 -> AoS out)
    final_kernel<<<(n + 4095) / 4096, 1024, DENSE_BYTES, stream>>>(x, wsh, out, n);
}